// Round 1
// baseline (375.222 us; speedup 1.0000x reference)
//
#include <hip/hip_runtime.h>
#include <math.h>

#define AS1 __attribute__((address_space(1)))
#define AS3 __attribute__((address_space(3)))

typedef _Float16 f16x8 __attribute__((ext_vector_type(8)));
typedef float f32x4 __attribute__((ext_vector_type(4)));

#define NROWS 8192
#define DDIM  512

// ---------------------------------------------------------------------------
// Kernel 1: per-row prep. One wave (64 lanes) per row; each lane owns 8 cols.
//  - xh[i,k] = f16(x[i,k])
//  - ah[i,k] = f16(x[i,k] * rho[k])
//  - mu_out[i] = sum_k x*muk + mu_bias   (fp32, wave-reduced)
//  - dvec[i]   = softplus(sum_k x*vark + var_bias) + 1e-8
// ---------------------------------------------------------------------------
__global__ __launch_bounds__(256) void prep_kernel(
    const float* __restrict__ x,
    const float* __restrict__ muk,
    const float* __restrict__ rho,
    const float* __restrict__ vark,
    const float* __restrict__ mu_bias,
    const float* __restrict__ var_bias,
    float* __restrict__ mu_out,
    _Float16* __restrict__ xh,
    _Float16* __restrict__ ah,
    float* __restrict__ dvec)
{
    const int wave = threadIdx.x >> 6;
    const int lane = threadIdx.x & 63;
    const int row  = blockIdx.x * 4 + wave;
    const int k    = lane * 8;

    const float4 x0 = *(const float4*)(x + (size_t)row * DDIM + k);
    const float4 x1 = *(const float4*)(x + (size_t)row * DDIM + k + 4);
    const float4 m0 = *(const float4*)(muk + k);
    const float4 m1 = *(const float4*)(muk + k + 4);
    const float4 r0 = *(const float4*)(rho + k);
    const float4 r1 = *(const float4*)(rho + k + 4);
    const float4 v0 = *(const float4*)(vark + k);
    const float4 v1 = *(const float4*)(vark + k + 4);

    float xv[8] = {x0.x, x0.y, x0.z, x0.w, x1.x, x1.y, x1.z, x1.w};
    float rv[8] = {r0.x, r0.y, r0.z, r0.w, r1.x, r1.y, r1.z, r1.w};
    float mv[8] = {m0.x, m0.y, m0.z, m0.w, m1.x, m1.y, m1.z, m1.w};
    float vv[8] = {v0.x, v0.y, v0.z, v0.w, v1.x, v1.y, v1.z, v1.w};

    f16x8 hx, ha;
    float dm = 0.f, dv = 0.f;
#pragma unroll
    for (int j = 0; j < 8; ++j) {
        hx[j] = (_Float16)xv[j];
        ha[j] = (_Float16)(xv[j] * rv[j]);
        dm += xv[j] * mv[j];
        dv += xv[j] * vv[j];
    }
    *(f16x8*)(xh + (size_t)row * DDIM + k) = hx;
    *(f16x8*)(ah + (size_t)row * DDIM + k) = ha;

#pragma unroll
    for (int off = 32; off > 0; off >>= 1) {
        dm += __shfl_down(dm, off, 64);
        dv += __shfl_down(dv, off, 64);
    }
    if (lane == 0) {
        mu_out[row] = dm + mu_bias[0];
        float z  = dv + var_bias[0];
        float sp = fmaxf(z, 0.f) + log1pf(expf(-fabsf(z)));  // stable softplus
        dvec[row] = sp + 1e-8f;
    }
}

// ---------------------------------------------------------------------------
// Kernel 2: C[i,j] = sum_k ah[i,k]*xh[j,k] + cov_bias ; C[i,i] = dvec[i].
// Symmetric => lower-triangular 128x128 blocks (bj<=bi), each off-diagonal
// block written in both orientations.
//
// Changes vs previous version:
//  - Double-buffered LDS: issue next k-tile's global_load_lds BEFORE the
//    current tile's ds_read+MFMA; the vmcnt(0) drain inside the single
//    end-of-iter __syncthreads now lands AFTER compute (T3 minimum 2-phase).
//    One barrier per k-step instead of two.
//  - Epilogue 1 vectorized: per-wave 16x20 fp32 LDS transpose (reusing As)
//    turns 64 scalar dword stores/thread into 16 float4 stores/thread.
//  - XCD-aware chunked block swizzle (nblk = 2080, 2080 % 8 == 0).
// ---------------------------------------------------------------------------
__device__ __forceinline__ void gload_lds16(const void* g, void* l)
{
    __builtin_amdgcn_global_load_lds((AS1 void*)g, (AS3 void*)l, 16, 0, 0);
}

__global__ __launch_bounds__(256) void cov_kernel(
    const _Float16* __restrict__ A,   // ah: 8192 x 512 (rows of x*rho)
    const _Float16* __restrict__ B,   // xh: 8192 x 512 (rows of x)
    const float* __restrict__ dvec,
    const float* __restrict__ cov_bias,
    float* __restrict__ C)
{
    __shared__ _Float16 As[2][128 * 32];   // 2 x 8 KB
    __shared__ _Float16 Bs[2][128 * 32];

    const int t    = threadIdx.x;
    const int lane = t & 63;
    const int wave = t >> 6;
    const int wr   = wave >> 1;         // 0..1 : 64-row half
    const int wc   = wave & 1;          // 0..1 : 64-col half
    const int quad = lane >> 4;         // 0..3
    const int l16  = lane & 15;

    // XCD-aware chunked swizzle: consecutive tt (same bi row-panel) land on
    // the same XCD's L2. 2080 % 8 == 0 -> simple form is bijective.
    const int bid = blockIdx.x;
    const int tt  = (bid & 7) * (2080 / 8) + (bid >> 3);

    // triangular decode: tt -> (bi, bj), bj <= bi
    int bi = (int)((sqrtf(8.f * (float)tt + 1.f) - 1.f) * 0.5f);
    while ((bi + 1) * (bi + 2) / 2 <= tt) ++bi;   // fixup fp rounding
    while (bi * (bi + 1) / 2 > tt) --bi;
    const int bj = tt - bi * (bi + 1) / 2;

    const int rowBase = bi * 128;
    const int colBase = bj * 128;
    const float cb = cov_bias[0];

    f32x4 acc[4][4] = {};

    // staging addresses: thread t loads 16 B (8 halves): row t>>2, chunk t&3
    const _Float16* ga = A + ((size_t)(rowBase + (t >> 2))) * DDIM + (t & 3) * 8;
    const _Float16* gb = B + ((size_t)(colBase + (t >> 2))) * DDIM + (t & 3) * 8;

    // prologue: stage k-tile 0 into buffer 0
    gload_lds16(ga,             As[0] + t * 8);
    gload_lds16(ga + 64 * DDIM, As[0] + 2048 + t * 8);
    gload_lds16(gb,             Bs[0] + t * 8);
    gload_lds16(gb + 64 * DDIM, Bs[0] + 2048 + t * 8);
    __syncthreads();

#pragma unroll 1
    for (int kt = 0; kt < 16; ++kt) {
        const int cur = kt & 1;

        // issue NEXT tile's loads first — their latency hides under this
        // tile's ds_read + MFMA; the drain happens at the end-of-iter barrier
        if (kt < 15) {
            const int k0 = (kt + 1) * 32;
            gload_lds16(ga + k0,             As[cur ^ 1] + t * 8);
            gload_lds16(ga + 64 * DDIM + k0, As[cur ^ 1] + 2048 + t * 8);
            gload_lds16(gb + k0,             Bs[cur ^ 1] + t * 8);
            gload_lds16(gb + 64 * DDIM + k0, Bs[cur ^ 1] + 2048 + t * 8);
        }

        f16x8 af[4], bf[4];
#pragma unroll
        for (int i = 0; i < 4; ++i)
            af[i] = *(const f16x8*)(As[cur] + (wr * 64 + i * 16 + l16) * 32 + quad * 8);
#pragma unroll
        for (int j = 0; j < 4; ++j)
            bf[j] = *(const f16x8*)(Bs[cur] + (wc * 64 + j * 16 + l16) * 32 + quad * 8);

#pragma unroll
        for (int i = 0; i < 4; ++i)
#pragma unroll
            for (int j = 0; j < 4; ++j)
                acc[i][j] = __builtin_amdgcn_mfma_f32_16x16x32_f16(af[i], bf[j], acc[i][j], 0, 0, 0);

        // single barrier per k-step: per-wave lgkmcnt(0) (ds_reads done) +
        // vmcnt(0) (next tile landed) + s_barrier
        __syncthreads();
    }

    // ---- epilogue 1: normal orientation via per-wave LDS transpose -> float4
    // C/D layout: col=lane&15, row=quad*4+reg. Transpose each 16x16 fragment
    // through a private 16x20 fp32 scratch (pad 20: 16B-aligned rows, <=2-way
    // bank aliasing which is free). After the loop's final __syncthreads all
    // waves are done with As -> safe to reuse.
    float* sc = (float*)(&As[0][0]) + wave * (16 * 20);   // 1280 B per wave

#pragma unroll
    for (int i = 0; i < 4; ++i) {
        const int grb = rowBase + wr * 64 + i * 16;
#pragma unroll
        for (int j = 0; j < 4; ++j) {
            const int gcb = colBase + wc * 64 + j * 16;
#pragma unroll
            for (int r = 0; r < 4; ++r)
                sc[(quad * 4 + r) * 20 + l16] = acc[i][j][r] + cb;
            // wave-private scratch: only wave-internal ordering needed
            asm volatile("s_waitcnt lgkmcnt(0)" ::: "memory");
            float4 v = *(const float4*)(sc + l16 * 20 + quad * 4);

            const int gr = grb + l16;         // row in C
            const int gc = gcb + quad * 4;    // first of 4 consecutive cols
            if (bi == bj) {
                const int c = gr - gc;
                if (0 <= c && c < 4) ((float*)&v)[c] = dvec[gr];
            }
            *(float4*)(C + (size_t)gr * NROWS + gc) = v;
            // DS ops from one wave execute in order: next iter's ds_write
            // cannot pass this iter's ds_read in the LDS pipe.
        }
    }

    // ---- epilogue 2: transposed orientation (off-diagonal blocks only).
    // acc[i][j][0..3] = 4 consecutive rows of one col => one float4 in the
    // transposed tile. Already vectorized.
    if (bi != bj) {
#pragma unroll
        for (int j = 0; j < 4; ++j) {
            const int trow = colBase + wc * 64 + j * 16 + l16;   // row in C
#pragma unroll
            for (int i = 0; i < 4; ++i) {
                const int tcol = rowBase + wr * 64 + i * 16 + quad * 4;
                float4 v;
                v.x = acc[i][j][0] + cb;
                v.y = acc[i][j][1] + cb;
                v.z = acc[i][j][2] + cb;
                v.w = acc[i][j][3] + cb;
                *(float4*)(C + (size_t)trow * NROWS + tcol) = v;
            }
        }
    }
}

// ---------------------------------------------------------------------------
extern "C" void kernel_launch(void* const* d_in, const int* in_sizes, int n_in,
                              void* d_out, int out_size, void* d_ws, size_t ws_size,
                              hipStream_t stream)
{
    const float* x     = (const float*)d_in[0];
    const float* muk   = (const float*)d_in[1];
    const float* rho   = (const float*)d_in[2];
    const float* vark  = (const float*)d_in[3];
    const float* mu_b  = (const float*)d_in[4];
    const float* var_b = (const float*)d_in[5];
    const float* cov_b = (const float*)d_in[6];

    float* out = (float*)d_out;                  // [0,8192): mu ; then cov row-major

    _Float16* xh = (_Float16*)d_ws;              // 8 MB
    _Float16* ah = xh + (size_t)NROWS * DDIM;    // 8 MB
    float* dvec  = (float*)(ah + (size_t)NROWS * DDIM);  // 32 KB

    prep_kernel<<<NROWS / 4, 256, 0, stream>>>(x, muk, rho, vark, mu_b, var_b,
                                               out, xh, ah, dvec);

    const int nblk = (NROWS / 128) * (NROWS / 128 + 1) / 2;   // 64*65/2 = 2080
    cov_kernel<<<nblk, 256, 0, stream>>>(ah, xh, dvec, cov_b, out + NROWS);
}

// Round 3
// 346.908 us; speedup vs baseline: 1.0816x; 1.0816x over previous
//
#include <hip/hip_runtime.h>
#include <math.h>

#define AS1 __attribute__((address_space(1)))
#define AS3 __attribute__((address_space(3)))

typedef _Float16 f16x8 __attribute__((ext_vector_type(8)));
typedef float f32x4 __attribute__((ext_vector_type(4)));

#define NROWS 8192
#define DDIM  512

// ---------------------------------------------------------------------------
// Kernel 1: per-row prep. One wave (64 lanes) per row; each lane owns 8 cols.
//  - xh[i,k] = f16(x[i,k])
//  - ah[i,k] = f16(x[i,k] * rho[k])
//  - mu_out[i] = sum_k x*muk + mu_bias   (fp32, wave-reduced)
//  - dvec[i]   = softplus(sum_k x*vark + var_bias) + 1e-8
// ---------------------------------------------------------------------------
__global__ __launch_bounds__(256) void prep_kernel(
    const float* __restrict__ x,
    const float* __restrict__ muk,
    const float* __restrict__ rho,
    const float* __restrict__ vark,
    const float* __restrict__ mu_bias,
    const float* __restrict__ var_bias,
    float* __restrict__ mu_out,
    _Float16* __restrict__ xh,
    _Float16* __restrict__ ah,
    float* __restrict__ dvec)
{
    const int wave = threadIdx.x >> 6;
    const int lane = threadIdx.x & 63;
    const int row  = blockIdx.x * 4 + wave;
    const int k    = lane * 8;

    const float4 x0 = *(const float4*)(x + (size_t)row * DDIM + k);
    const float4 x1 = *(const float4*)(x + (size_t)row * DDIM + k + 4);
    const float4 m0 = *(const float4*)(muk + k);
    const float4 m1 = *(const float4*)(muk + k + 4);
    const float4 r0 = *(const float4*)(rho + k);
    const float4 r1 = *(const float4*)(rho + k + 4);
    const float4 v0 = *(const float4*)(vark + k);
    const float4 v1 = *(const float4*)(vark + k + 4);

    float xv[8] = {x0.x, x0.y, x0.z, x0.w, x1.x, x1.y, x1.z, x1.w};
    float rv[8] = {r0.x, r0.y, r0.z, r0.w, r1.x, r1.y, r1.z, r1.w};
    float mv[8] = {m0.x, m0.y, m0.z, m0.w, m1.x, m1.y, m1.z, m1.w};
    float vv[8] = {v0.x, v0.y, v0.z, v0.w, v1.x, v1.y, v1.z, v1.w};

    f16x8 hx, ha;
    float dm = 0.f, dv = 0.f;
#pragma unroll
    for (int j = 0; j < 8; ++j) {
        hx[j] = (_Float16)xv[j];
        ha[j] = (_Float16)(xv[j] * rv[j]);
        dm += xv[j] * mv[j];
        dv += xv[j] * vv[j];
    }
    *(f16x8*)(xh + (size_t)row * DDIM + k) = hx;
    *(f16x8*)(ah + (size_t)row * DDIM + k) = ha;

#pragma unroll
    for (int off = 32; off > 0; off >>= 1) {
        dm += __shfl_down(dm, off, 64);
        dv += __shfl_down(dv, off, 64);
    }
    if (lane == 0) {
        mu_out[row] = dm + mu_bias[0];
        float z  = dv + var_bias[0];
        float sp = fmaxf(z, 0.f) + log1pf(expf(-fabsf(z)));  // stable softplus
        dvec[row] = sp + 1e-8f;
    }
}

// ---------------------------------------------------------------------------
// Kernel 2: C[i,j] = sum_k ah[i,k]*xh[j,k] + cov_bias ; C[i,i] = dvec[i].
// Symmetric => lower-triangular 128x128 blocks (bj<=bi), off-diagonal blocks
// written in both orientations.
//
// v2 (resubmit after infra failure):
//  - T3+T4: depth-2 prefetch pipeline with COUNTED vmcnt. 3 LDS slots
//    (48 KB, 3 blocks/CU). Steady state: vmcnt(8) = "tile t+1 landed,
//    tiles t+2/t+3 still in flight" -> L2/L3 load latency (~400-600 cyc)
//    hidden under ~2 compute phases. Never drain vmcnt(0) mid-loop.
//  - T2-style bank-conflict fix for the ds_read_b128 fragment reads.
//    Rule 21: LDS dest stays LINEAR (global_load_lds requirement); the
//    global SOURCE chunk is pre-swizzled (g = c ^ ((row>>1)&3)) and the
//    read applies the same XOR (chunk = quad ^ ((l16>>1)&3)). Residual
//    aliasing 2-way = free (m136).
//  - Epilogue = v0's direct stores (measured faster than LDS transpose);
//    diag branch hoisted out of the 2016 off-diagonal blocks.
//  - XCD-aware chunked block swizzle (2080 % 8 == 0, bijective).
// ---------------------------------------------------------------------------
__device__ __forceinline__ void gload_lds16(const void* g, void* l)
{
    __builtin_amdgcn_global_load_lds((AS1 void*)g, (AS3 void*)l, 16, 0, 0);
}

__global__ __launch_bounds__(256) void cov_kernel(
    const _Float16* __restrict__ A,   // ah: 8192 x 512 (rows of x*rho)
    const _Float16* __restrict__ B,   // xh: 8192 x 512 (rows of x)
    const float* __restrict__ dvec,
    const float* __restrict__ cov_bias,
    float* __restrict__ C)
{
    __shared__ _Float16 As[3][128 * 32];   // 3 x 8 KB
    __shared__ _Float16 Bs[3][128 * 32];

    const int t    = threadIdx.x;
    const int lane = t & 63;
    const int wave = t >> 6;
    const int wr   = wave >> 1;         // 0..1 : 64-row half
    const int wc   = wave & 1;          // 0..1 : 64-col half
    const int quad = lane >> 4;         // 0..3
    const int l16  = lane & 15;
    const int xc   = quad ^ ((l16 >> 1) & 3);   // swizzled read chunk

    // XCD-aware chunked swizzle (2080 % 8 == 0 -> bijective simple form)
    const int bid = blockIdx.x;
    const int tt  = (bid & 7) * (2080 / 8) + (bid >> 3);

    // triangular decode: tt -> (bi, bj), bj <= bi
    int bi = (int)((sqrtf(8.f * (float)tt + 1.f) - 1.f) * 0.5f);
    while ((bi + 1) * (bi + 2) / 2 <= tt) ++bi;   // fixup fp rounding
    while (bi * (bi + 1) / 2 > tt) --bi;
    const int bj = tt - bi * (bi + 1) / 2;

    const int rowBase = bi * 128;
    const int colBase = bj * 128;
    const float cb = cov_bias[0];

    f32x4 acc[4][4] = {};

    // staging: thread t owns LDS slot (row r = t>>2, chunk c = t&3, 16 B).
    // Pre-swizzled global source chunk g = c ^ ((r>>1)&3)  (rule 21).
    const int sr = t >> 2;
    const int sg = (t & 3) ^ ((sr >> 1) & 3);
    const _Float16* ga = A + ((size_t)(rowBase + sr)) * DDIM + sg * 8;
    const _Float16* gb = B + ((size_t)(colBase + sr)) * DDIM + sg * 8;

#define STAGE(kt, s) do {                                            \
        const int _k0 = (kt) * 32;                                   \
        gload_lds16(ga + _k0,             As[s] + t * 8);            \
        gload_lds16(ga + 64 * DDIM + _k0, As[s] + 2048 + t * 8);     \
        gload_lds16(gb + _k0,             Bs[s] + t * 8);            \
        gload_lds16(gb + 64 * DDIM + _k0, Bs[s] + 2048 + t * 8);     \
    } while (0)

    f16x8 af[4], bf[4];

#define DSREAD(s) do {                                                          \
        _Pragma("unroll")                                                       \
        for (int _i = 0; _i < 4; ++_i)                                          \
            af[_i] = *(const f16x8*)(As[s] + (wr * 64 + _i * 16 + l16) * 32 + xc * 8); \
        _Pragma("unroll")                                                       \
        for (int _j = 0; _j < 4; ++_j)                                          \
            bf[_j] = *(const f16x8*)(Bs[s] + (wc * 64 + _j * 16 + l16) * 32 + xc * 8); \
    } while (0)

#define DOMFMA() do {                                                           \
        _Pragma("unroll")                                                       \
        for (int _i = 0; _i < 4; ++_i)                                          \
            _Pragma("unroll")                                                   \
            for (int _j = 0; _j < 4; ++_j)                                      \
                acc[_i][_j] = __builtin_amdgcn_mfma_f32_16x16x32_f16(           \
                    af[_i], bf[_j], acc[_i][_j], 0, 0, 0);                      \
    } while (0)

    // prologue: fill the pipeline 3 tiles deep, wait for tile 0 only
    STAGE(0, 0);
    STAGE(1, 1);
    STAGE(2, 2);
    asm volatile("s_waitcnt vmcnt(8)" ::: "memory");   // tile 0 landed
    __builtin_amdgcn_s_barrier();

    // main loop: tiles 0..12. Slot s = kt%3 is read, then (after all waves
    // finished reading: lgkmcnt(0) + barrier) re-staged with tile kt+3.
    // End-of-iter: vmcnt(8) = tile kt+1 landed (kt+2, kt+3 stay in flight).
#pragma unroll 1
    for (int kt = 0; kt < 13; ++kt) {
        const int s = kt % 3;
        DSREAD(s);
        asm volatile("s_waitcnt lgkmcnt(0)" ::: "memory");
        __builtin_amdgcn_s_barrier();
        STAGE(kt + 3, s);
        DOMFMA();
        asm volatile("s_waitcnt vmcnt(8)" ::: "memory");
        __builtin_amdgcn_s_barrier();
    }

    // tail: tiles 13,14,15 — no more staging; drain counted
    DSREAD(1);                                          // tile 13
    DOMFMA();
    asm volatile("s_waitcnt vmcnt(4)" ::: "memory");    // tile 14 landed
    __builtin_amdgcn_s_barrier();

    DSREAD(2);                                          // tile 14
    DOMFMA();
    asm volatile("s_waitcnt vmcnt(0)" ::: "memory");    // tile 15 landed
    __builtin_amdgcn_s_barrier();

    DSREAD(0);                                          // tile 15
    DOMFMA();

#undef STAGE
#undef DSREAD
#undef DOMFMA

    // ---- epilogue 1: normal orientation (v0-proven direct stores).
    // C/D layout: col=lane&15, row=quad*4+reg. 4x 64B segments per store.
    if (bi == bj) {
#pragma unroll
        for (int i = 0; i < 4; ++i) {
            const int grb = rowBase + wr * 64 + i * 16 + quad * 4;
#pragma unroll
            for (int j = 0; j < 4; ++j) {
                const int gc = colBase + wc * 64 + j * 16 + l16;
#pragma unroll
                for (int r = 0; r < 4; ++r) {
                    const int gr = grb + r;
                    float v = acc[i][j][r] + cb;
                    if (gr == gc) v = dvec[gr];
                    C[(size_t)gr * NROWS + gc] = v;
                }
            }
        }
    } else {
#pragma unroll
        for (int i = 0; i < 4; ++i) {
            const int grb = rowBase + wr * 64 + i * 16 + quad * 4;
#pragma unroll
            for (int j = 0; j < 4; ++j) {
                const int gc = colBase + wc * 64 + j * 16 + l16;
#pragma unroll
                for (int r = 0; r < 4; ++r)
                    C[(size_t)(grb + r) * NROWS + gc] = acc[i][j][r] + cb;
            }
        }

        // ---- epilogue 2: transposed orientation. acc[i][j][0..3] are 4
        // consecutive rows of one col => one float4 in the transposed tile.
#pragma unroll
        for (int j = 0; j < 4; ++j) {
            const int trow = colBase + wc * 64 + j * 16 + l16;   // row in C
#pragma unroll
            for (int i = 0; i < 4; ++i) {
                const int tcol = rowBase + wr * 64 + i * 16 + quad * 4;
                float4 v;
                v.x = acc[i][j][0] + cb;
                v.y = acc[i][j][1] + cb;
                v.z = acc[i][j][2] + cb;
                v.w = acc[i][j][3] + cb;
                *(float4*)(C + (size_t)trow * NROWS + tcol) = v;
            }
        }
    }
}

// ---------------------------------------------------------------------------
extern "C" void kernel_launch(void* const* d_in, const int* in_sizes, int n_in,
                              void* d_out, int out_size, void* d_ws, size_t ws_size,
                              hipStream_t stream)
{
    const float* x     = (const float*)d_in[0];
    const float* muk   = (const float*)d_in[1];
    const float* rho   = (const float*)d_in[2];
    const float* vark  = (const float*)d_in[3];
    const float* mu_b  = (const float*)d_in[4];
    const float* var_b = (const float*)d_in[5];
    const float* cov_b = (const float*)d_in[6];

    float* out = (float*)d_out;                  // [0,8192): mu ; then cov row-major

    _Float16* xh = (_Float16*)d_ws;              // 8 MB
    _Float16* ah = xh + (size_t)NROWS * DDIM;    // 8 MB
    float* dvec  = (float*)(ah + (size_t)NROWS * DDIM);  // 32 KB

    prep_kernel<<<NROWS / 4, 256, 0, stream>>>(x, muk, rho, vark, mu_b, var_b,
                                               out, xh, ah, dvec);

    const int nblk = (NROWS / 128) * (NROWS / 128 + 1) / 2;   // 64*65/2 = 2080
    cov_kernel<<<nblk, 256, 0, stream>>>(ah, xh, dvec, cov_b, out + NROWS);
}

// Round 5
// 334.961 us; speedup vs baseline: 1.1202x; 1.0357x over previous
//
#include <hip/hip_runtime.h>
#include <math.h>

#define AS1 __attribute__((address_space(1)))
#define AS3 __attribute__((address_space(3)))

typedef _Float16 f16x8 __attribute__((ext_vector_type(8)));
typedef float f32x4 __attribute__((ext_vector_type(4)));

#define NROWS 8192
#define DDIM  512

// ---------------------------------------------------------------------------
// Kernel 1: per-row prep. One wave (64 lanes) per row; each lane owns 8 cols.
// ---------------------------------------------------------------------------
__global__ __launch_bounds__(256) void prep_kernel(
    const float* __restrict__ x,
    const float* __restrict__ muk,
    const float* __restrict__ rho,
    const float* __restrict__ vark,
    const float* __restrict__ mu_bias,
    const float* __restrict__ var_bias,
    float* __restrict__ mu_out,
    _Float16* __restrict__ xh,
    _Float16* __restrict__ ah,
    float* __restrict__ dvec)
{
    const int wave = threadIdx.x >> 6;
    const int lane = threadIdx.x & 63;
    const int row  = blockIdx.x * 4 + wave;
    const int k    = lane * 8;

    const float4 x0 = *(const float4*)(x + (size_t)row * DDIM + k);
    const float4 x1 = *(const float4*)(x + (size_t)row * DDIM + k + 4);
    const float4 m0 = *(const float4*)(muk + k);
    const float4 m1 = *(const float4*)(muk + k + 4);
    const float4 r0 = *(const float4*)(rho + k);
    const float4 r1 = *(const float4*)(rho + k + 4);
    const float4 v0 = *(const float4*)(vark + k);
    const float4 v1 = *(const float4*)(vark + k + 4);

    float xv[8] = {x0.x, x0.y, x0.z, x0.w, x1.x, x1.y, x1.z, x1.w};
    float rv[8] = {r0.x, r0.y, r0.z, r0.w, r1.x, r1.y, r1.z, r1.w};
    float mv[8] = {m0.x, m0.y, m0.z, m0.w, m1.x, m1.y, m1.z, m1.w};
    float vv[8] = {v0.x, v0.y, v0.z, v0.w, v1.x, v1.y, v1.z, v1.w};

    f16x8 hx, ha;
    float dm = 0.f, dv = 0.f;
#pragma unroll
    for (int j = 0; j < 8; ++j) {
        hx[j] = (_Float16)xv[j];
        ha[j] = (_Float16)(xv[j] * rv[j]);
        dm += xv[j] * mv[j];
        dv += xv[j] * vv[j];
    }
    *(f16x8*)(xh + (size_t)row * DDIM + k) = hx;
    *(f16x8*)(ah + (size_t)row * DDIM + k) = ha;

#pragma unroll
    for (int off = 32; off > 0; off >>= 1) {
        dm += __shfl_down(dm, off, 64);
        dv += __shfl_down(dv, off, 64);
    }
    if (lane == 0) {
        mu_out[row] = dm + mu_bias[0];
        float z  = dv + var_bias[0];
        float sp = fmaxf(z, 0.f) + log1pf(expf(-fabsf(z)));  // stable softplus
        dvec[row] = sp + 1e-8f;
    }
}

// ---------------------------------------------------------------------------
// Kernel 2: C[i,j] = sum_k ah[i,k]*xh[j,k] + cov_bias ; C[i,i] = dvec[i].
// Symmetric => lower-triangular 128x128 blocks (bj<=bi), off-diagonal blocks
// written in both orientations.
//
// v3 theory: cov is HBM-bound on PANEL RE-READS (532 MB re-read traffic
// misses L3 because the 268 MB C-write stream + the harness's 1.07 GB poison
// fill continuously flush it; 800 MB @ ~5.2 TB/s == the measured ~155 us).
// Changes:
//  - CELL-MAJOR block order: 8x8-block supertiles (cells). One cell touches
//    8 A-panels + 8 B-panels = 2 MB -> fits an XCD's 4 MB L2. HBM reads drop
//    ~532 MB -> ~72-100 MB. XCD chunked swizzle on top (260 tt per XCD ~= 4
//    consecutive cells).
//  - NON-TEMPORAL C stores ('nt' flag): the write stream stops evicting the
//    xh/ah panels from L2/L3.  (v4: ext-vector f32x4 for the NT vector
//    store — the builtin rejects HIP_vector_type float4*.)
//  - Core loop unchanged from v2 (counted vmcnt depth-2, read swizzle) —
//    measured neutral, kept for schedule robustness.
// ---------------------------------------------------------------------------
__device__ __forceinline__ void gload_lds16(const void* g, void* l)
{
    __builtin_amdgcn_global_load_lds((AS1 void*)g, (AS3 void*)l, 16, 0, 0);
}

__global__ __launch_bounds__(256) void cov_kernel(
    const _Float16* __restrict__ A,   // ah: 8192 x 512 (rows of x*rho)
    const _Float16* __restrict__ B,   // xh: 8192 x 512 (rows of x)
    const float* __restrict__ dvec,
    const float* __restrict__ cov_bias,
    float* __restrict__ C)
{
    __shared__ _Float16 As[3][128 * 32];   // 3 x 8 KB
    __shared__ _Float16 Bs[3][128 * 32];

    const int t    = threadIdx.x;
    const int lane = t & 63;
    const int wave = t >> 6;
    const int wr   = wave >> 1;         // 0..1 : 64-row half
    const int wc   = wave & 1;          // 0..1 : 64-col half
    const int quad = lane >> 4;         // 0..3
    const int l16  = lane & 15;
    const int xc   = quad ^ ((l16 >> 1) & 3);   // swizzled read chunk

    // XCD-aware chunked swizzle (2080 % 8 == 0 -> bijective simple form).
    // tt enumerates blocks in CELL-MAJOR order (see decode below), so each
    // XCD's contiguous 260-range covers ~4 cells -> L2-sized working set.
    const int bid = blockIdx.x;
    const int tt  = (bid & 7) * 260 + (bid >> 3);

    // cell-major decode: cells are 8x8 blocks; cell-row SI has SI full cells
    // (64 blocks) + 1 diagonal cell (36 blocks).
    // blocks before cell-row SI: base(SI) = 32*SI^2 + 4*SI
    int SI = (int)((sqrtf(1.f + 8.f * (float)tt) - 1.f) * 0.0625f);
    while (32 * (SI + 1) * (SI + 1) + 4 * (SI + 1) <= tt) ++SI;
    while (32 * SI * SI + 4 * SI > tt) --SI;
    const int rem = tt - (32 * SI * SI + 4 * SI);
    int SJ, ii, jj;
    if (rem < 64 * SI) {                 // full off-diagonal cell
        SJ = rem >> 6;
        const int w = rem & 63;
        ii = w >> 3;
        jj = w & 7;
    } else {                             // diagonal cell: 36 blocks, jj<=ii
        const int w = rem - 64 * SI;
        SJ = SI;
        ii = (int)((sqrtf(8.f * (float)w + 1.f) - 1.f) * 0.5f);
        while ((ii + 1) * (ii + 2) / 2 <= w) ++ii;
        while (ii * (ii + 1) / 2 > w) --ii;
        jj = w - ii * (ii + 1) / 2;
    }
    const int bi = SI * 8 + ii;
    const int bj = SJ * 8 + jj;

    const int rowBase = bi * 128;
    const int colBase = bj * 128;
    const float cb = cov_bias[0];

    f32x4 acc[4][4] = {};

    // staging: thread t owns LDS slot (row r = t>>2, chunk c = t&3, 16 B).
    // Pre-swizzled global source chunk g = c ^ ((r>>1)&3)  (rule 21).
    const int sr = t >> 2;
    const int sg = (t & 3) ^ ((sr >> 1) & 3);
    const _Float16* ga = A + ((size_t)(rowBase + sr)) * DDIM + sg * 8;
    const _Float16* gb = B + ((size_t)(colBase + sr)) * DDIM + sg * 8;

#define STAGE(kt, s) do {                                            \
        const int _k0 = (kt) * 32;                                   \
        gload_lds16(ga + _k0,             As[s] + t * 8);            \
        gload_lds16(ga + 64 * DDIM + _k0, As[s] + 2048 + t * 8);     \
        gload_lds16(gb + _k0,             Bs[s] + t * 8);            \
        gload_lds16(gb + 64 * DDIM + _k0, Bs[s] + 2048 + t * 8);     \
    } while (0)

    f16x8 af[4], bf[4];

#define DSREAD(s) do {                                                          \
        _Pragma("unroll")                                                       \
        for (int _i = 0; _i < 4; ++_i)                                          \
            af[_i] = *(const f16x8*)(As[s] + (wr * 64 + _i * 16 + l16) * 32 + xc * 8); \
        _Pragma("unroll")                                                       \
        for (int _j = 0; _j < 4; ++_j)                                          \
            bf[_j] = *(const f16x8*)(Bs[s] + (wc * 64 + _j * 16 + l16) * 32 + xc * 8); \
    } while (0)

#define DOMFMA() do {                                                           \
        _Pragma("unroll")                                                       \
        for (int _i = 0; _i < 4; ++_i)                                          \
            _Pragma("unroll")                                                   \
            for (int _j = 0; _j < 4; ++_j)                                      \
                acc[_i][_j] = __builtin_amdgcn_mfma_f32_16x16x32_f16(           \
                    af[_i], bf[_j], acc[_i][_j], 0, 0, 0);                      \
    } while (0)

    // prologue: fill the pipeline 3 tiles deep, wait for tile 0 only
    STAGE(0, 0);
    STAGE(1, 1);
    STAGE(2, 2);
    asm volatile("s_waitcnt vmcnt(8)" ::: "memory");   // tile 0 landed
    __builtin_amdgcn_s_barrier();

#pragma unroll 1
    for (int kt = 0; kt < 13; ++kt) {
        const int s = kt % 3;
        DSREAD(s);
        asm volatile("s_waitcnt lgkmcnt(0)" ::: "memory");
        __builtin_amdgcn_s_barrier();
        STAGE(kt + 3, s);
        DOMFMA();
        asm volatile("s_waitcnt vmcnt(8)" ::: "memory");
        __builtin_amdgcn_s_barrier();
    }

    // tail: tiles 13,14,15 — no more staging; drain counted
    DSREAD(1);                                          // tile 13
    DOMFMA();
    asm volatile("s_waitcnt vmcnt(4)" ::: "memory");    // tile 14 landed
    __builtin_amdgcn_s_barrier();

    DSREAD(2);                                          // tile 14
    DOMFMA();
    asm volatile("s_waitcnt vmcnt(0)" ::: "memory");    // tile 15 landed
    __builtin_amdgcn_s_barrier();

    DSREAD(0);                                          // tile 15
    DOMFMA();

#undef STAGE
#undef DSREAD
#undef DOMFMA

    // ---- epilogue 1: normal orientation, NON-TEMPORAL stores.
    // C/D layout: col=lane&15, row=quad*4+reg.
    if (bi == bj) {
#pragma unroll
        for (int i = 0; i < 4; ++i) {
            const int grb = rowBase + wr * 64 + i * 16 + quad * 4;
#pragma unroll
            for (int j = 0; j < 4; ++j) {
                const int gc = colBase + wc * 64 + j * 16 + l16;
#pragma unroll
                for (int r = 0; r < 4; ++r) {
                    const int gr = grb + r;
                    float v = acc[i][j][r] + cb;
                    if (gr == gc) v = dvec[gr];
                    __builtin_nontemporal_store(v, C + (size_t)gr * NROWS + gc);
                }
            }
        }
    } else {
#pragma unroll
        for (int i = 0; i < 4; ++i) {
            const int grb = rowBase + wr * 64 + i * 16 + quad * 4;
#pragma unroll
            for (int j = 0; j < 4; ++j) {
                const int gc = colBase + wc * 64 + j * 16 + l16;
#pragma unroll
                for (int r = 0; r < 4; ++r)
                    __builtin_nontemporal_store(acc[i][j][r] + cb,
                                                C + (size_t)(grb + r) * NROWS + gc);
            }
        }

        // ---- epilogue 2: transposed orientation, f32x4 non-temporal.
#pragma unroll
        for (int j = 0; j < 4; ++j) {
            const int trow = colBase + wc * 64 + j * 16 + l16;   // row in C
#pragma unroll
            for (int i = 0; i < 4; ++i) {
                const int tcol = rowBase + wr * 64 + i * 16 + quad * 4;
                f32x4 v;
                v[0] = acc[i][j][0] + cb;
                v[1] = acc[i][j][1] + cb;
                v[2] = acc[i][j][2] + cb;
                v[3] = acc[i][j][3] + cb;
                __builtin_nontemporal_store(v, (f32x4*)(C + (size_t)trow * NROWS + tcol));
            }
        }
    }
}

// ---------------------------------------------------------------------------
extern "C" void kernel_launch(void* const* d_in, const int* in_sizes, int n_in,
                              void* d_out, int out_size, void* d_ws, size_t ws_size,
                              hipStream_t stream)
{
    const float* x     = (const float*)d_in[0];
    const float* muk   = (const float*)d_in[1];
    const float* rho   = (const float*)d_in[2];
    const float* vark  = (const float*)d_in[3];
    const float* mu_b  = (const float*)d_in[4];
    const float* var_b = (const float*)d_in[5];
    const float* cov_b = (const float*)d_in[6];

    float* out = (float*)d_out;                  // [0,8192): mu ; then cov row-major

    _Float16* xh = (_Float16*)d_ws;              // 8 MB
    _Float16* ah = xh + (size_t)NROWS * DDIM;    // 8 MB
    float* dvec  = (float*)(ah + (size_t)NROWS * DDIM);  // 32 KB

    prep_kernel<<<NROWS / 4, 256, 0, stream>>>(x, muk, rho, vark, mu_b, var_b,
                                               out, xh, ah, dvec);

    const int nblk = (NROWS / 128) * (NROWS / 128 + 1) / 2;   // 64*65/2 = 2080
    cov_kernel<<<nblk, 256, 0, stream>>>(ah, xh, dvec, cov_b, out + NROWS);
}